// Round 2
// baseline (721.967 us; speedup 1.0000x reference)
//
#include <hip/hip_runtime.h>

// ---------------------------------------------------------------------------
// GraphAggregator v3: DMA-staged x (global_load_lds, fp32), 3-slab rotation,
// counted-vmcnt barriers so prefetch DMAs stay in flight (T3/T4-lite).
//  - x staged fp32 via global_load_lds: per-lane swizzled SOURCE, linear LDS
//    dest (m173 pattern). No reg staging, no pack VALU, no ds_write conflicts.
//  - B fragments global->VGPR from L2-hot blob, issued BEFORE the phase DMA
//    (vmcnt FIFO: MFMA's B-wait then leaves the DMA outstanding).
//  - bf16 conversion at fragment-read time via v_cvt_pk_bf16_f32 (HW RNE).
//  - barriers: asm s_waitcnt vmcnt(1) lgkmcnt(0); s_barrier (never vmcnt(0)
//    in steady state).
//  - sums zeroing folded into prep_w (one less dispatch).
// ---------------------------------------------------------------------------

typedef __attribute__((ext_vector_type(8))) short bf16x8;
typedef __attribute__((ext_vector_type(4))) float f32x4;

__device__ __forceinline__ short f2bf(float f) {
  unsigned u = __float_as_uint(f);
  unsigned r = (u + 0x7FFFu + ((u >> 16) & 1u)) >> 16;   // RNE
  return (short)r;
}

__device__ __forceinline__ void glds16f(float* ldst, const float* gsrc) {
  __builtin_amdgcn_global_load_lds(
      (const __attribute__((address_space(1))) void*)gsrc,
      (__attribute__((address_space(3))) void*)ldst,
      16, 0, 0);
}

// 8 fp32 -> bf16x8 via 4x v_cvt_pk_bf16_f32 (RNE in HW)
__device__ __forceinline__ bf16x8 cvt8(f32x4 lo, f32x4 hi) {
  union { unsigned u[4]; bf16x8 v; } cv;
  asm("v_cvt_pk_bf16_f32 %0, %4, %5\n\t"
      "v_cvt_pk_bf16_f32 %1, %6, %7\n\t"
      "v_cvt_pk_bf16_f32 %2, %8, %9\n\t"
      "v_cvt_pk_bf16_f32 %3, %10, %11"
      : "=&v"(cv.u[0]), "=&v"(cv.u[1]), "=&v"(cv.u[2]), "=&v"(cv.u[3])
      : "v"(lo[0]), "v"(lo[1]), "v"(lo[2]), "v"(lo[3]),
        "v"(hi[0]), "v"(hi[1]), "v"(hi[2]), "v"(hi[3]));
  return cv.v;
}

// ---------------------------------------------------------------------------
// prep_w: fp32 W[k][n] (256x256) -> bf16 blob in MFMA B-fragment order:
//   blob[mat][ks][ct*64+lane][j] = W[ks*32 + (lane>>4)*8 + j][ct*16 + (lane&15)]
// mat 0 = W_gate, mat 1 = W_lin. One block per (mat, ks) slice.
// Also zeroes the sums buffer (replaces hipMemsetAsync).
// ---------------------------------------------------------------------------
__global__ __launch_bounds__(256) void prep_w(const float* __restrict__ Wg,
                                              const float* __restrict__ Wl,
                                              short* __restrict__ blob,
                                              float* __restrict__ sums) {
  __shared__ __align__(16) float tile[32][260];
  const int b = blockIdx.x;
  const int mat = b >> 3, ks = b & 7;
  const float* W = mat ? Wl : Wg;
  const int tid = threadIdx.x;
  // zero sums: 512*256 floats = 32768 f32x4 over 16*256 threads -> 8 each
  {
    f32x4 z = (f32x4)(0.0f);
    #pragma unroll
    for (int i = 0; i < 8; ++i)
      *(f32x4*)&sums[(size_t)(i * 4096 + b * 256 + tid) * 4] = z;
  }
  #pragma unroll
  for (int i = 0; i < 8; ++i) {
    int f4 = tid + i * 256;
    int kl = f4 >> 6;
    int c0 = (f4 & 63) * 4;
    f32x4 v = *(const f32x4*)&W[(ks * 32 + kl) * 256 + c0];
    tile[kl][c0 + 0] = v[0]; tile[kl][c0 + 1] = v[1];
    tile[kl][c0 + 2] = v[2]; tile[kl][c0 + 3] = v[3];
  }
  __syncthreads();
  #pragma unroll
  for (int i = 0; i < 4; ++i) {
    int chunk = tid + i * 256;           // ct*64 + lane
    int ln = chunk & 63;
    int n  = ((chunk >> 6) << 4) + (ln & 15);
    int k0 = (ln >> 4) * 8;
    bf16x8 o;
    #pragma unroll
    for (int j = 0; j < 8; ++j) o[j] = f2bf(tile[k0 + j][n]);
    *(bf16x8*)&blob[(size_t)(mat * 8 + ks) * 8192 + (size_t)chunk * 8] = o;
  }
}

// ---------------------------------------------------------------------------
// fused_main: 64 rows/block, 512 threads (8 waves), wave = col-group
// (32 cols x 2 mats each). Per wave per phase: 4 A-frags x 4 B-frags,
// 16 MFMA (16x16x32 bf16).
// LDS x-slab layout (fp32): chunk c = r*64+lane holds x[r*16+(lane&15)]
// [k: (lane>>4)*8 .. +7]; slab = 2048 floats; 3 slabs rotate.
// DMA granule tid writes chunk tid>>1, half tid&1 (dest = linear tid*16B).
// ---------------------------------------------------------------------------
__global__ __launch_bounds__(512, 4) void
fused_main(const float* __restrict__ x,
           const int* __restrict__ batch,
           const float* __restrict__ b_lin,
           const float* __restrict__ b_gate,
           const short* __restrict__ blob,
           float* __restrict__ sums) {
  __shared__ __align__(16) float xsf[3 * 2048];   // 3 fp32 slabs, 24 KB
  __shared__ __align__(16) float pmax[64 * 8];    // [row][wave] 2 KB
  __shared__ __align__(16) float psum[64 * 8];    // 2 KB
  __shared__ int batch_l[64];

  const int tid  = threadIdx.x;
  const int lane = tid & 63;
  const int wave = tid >> 6;            // col-group 0..7 (32 cols each)
  const int quad = lane >> 4;
  const int ln15 = lane & 15;
  const long long row0 = (long long)blockIdx.x * 64;

  // staging source mapping: granule index = tid
  const int g_r = tid >> 7;             // row-tile 0..3
  const int g_l = (tid >> 1) & 63;      // reading lane of that chunk
  const int g_h = tid & 1;              // 16B half of the 32B chunk
  const float* xsrc = x + (row0 + g_r * 16 + (g_l & 15)) * 256
                        + (g_l >> 4) * 8 + g_h * 4;
  float* dma_dst = xsf + wave * 256;    // wave-uniform; HW adds lane*16B

  const short* bptr = blob + (size_t)(wave * 128 + lane) * 8;

  // ---- prologue: batch tile, B(0) regs (oldest in vmcnt FIFO), 2 DMAs ----
  if (tid < 64) batch_l[tid] = batch[row0 + tid];
  bf16x8 bz0 = *(const bf16x8*)(bptr);
  bf16x8 bz1 = *(const bf16x8*)(bptr + 512);
  bf16x8 bs0 = *(const bf16x8*)(bptr + (size_t)8 * 8192);
  bf16x8 bs1 = *(const bf16x8*)(bptr + (size_t)8 * 8192 + 512);
  __builtin_amdgcn_sched_barrier(0);
  glds16f(dma_dst, xsrc);                       // slab 0 (ks=0)
  glds16f(dma_dst + 2048, xsrc + 32);           // slab 1 (ks=1)
  asm volatile("s_waitcnt vmcnt(1) lgkmcnt(0)\ns_barrier" ::: "memory");

  f32x4 accz[4][2], accs[4][2];
  #pragma unroll
  for (int r = 0; r < 4; ++r)
    #pragma unroll
    for (int c = 0; c < 2; ++c) {
      accz[r][c] = (f32x4)(0.0f);
      accs[r][c] = (f32x4)(0.0f);
    }

  #pragma unroll
  for (int ks = 0; ks < 8; ++ks) {
    if (ks > 0) {
      bz0 = *(const bf16x8*)(bptr + (size_t)ks * 8192);
      bz1 = *(const bf16x8*)(bptr + (size_t)ks * 8192 + 512);
      bs0 = *(const bf16x8*)(bptr + (size_t)(8 + ks) * 8192);
      bs1 = *(const bf16x8*)(bptr + (size_t)(8 + ks) * 8192 + 512);
    }
    __builtin_amdgcn_sched_barrier(0);   // keep B loads older than the DMA
    if (ks < 6)
      glds16f(xsf + ((ks + 2) % 3) * 2048 + wave * 256, xsrc + (ks + 2) * 32);
    const float* xb = xsf + (ks % 3) * 2048;
    #pragma unroll
    for (int r = 0; r < 4; ++r) {
      f32x4 lo = *(const f32x4*)(xb + (r * 64 + lane) * 8);
      f32x4 hi = *(const f32x4*)(xb + (r * 64 + lane) * 8 + 4);
      bf16x8 a = cvt8(lo, hi);
      accz[r][0] = __builtin_amdgcn_mfma_f32_16x16x32_bf16(a, bz0, accz[r][0], 0, 0, 0);
      accz[r][1] = __builtin_amdgcn_mfma_f32_16x16x32_bf16(a, bz1, accz[r][1], 0, 0, 0);
      accs[r][0] = __builtin_amdgcn_mfma_f32_16x16x32_bf16(a, bs0, accs[r][0], 0, 0, 0);
      accs[r][1] = __builtin_amdgcn_mfma_f32_16x16x32_bf16(a, bs1, accs[r][1], 0, 0, 0);
    }
    // steady state: exactly one DMA (slab ks+2) outstanding -> vmcnt(1)
    if (ks < 6)
      asm volatile("s_waitcnt vmcnt(1) lgkmcnt(0)\ns_barrier" ::: "memory");
    else if (ks == 6)
      asm volatile("s_waitcnt vmcnt(0) lgkmcnt(0)\ns_barrier" ::: "memory");
  }

  // ---- biases ----
  const float bg0 = b_gate[wave * 32 + ln15];
  const float bg1 = b_gate[wave * 32 + 16 + ln15];
  const float bl0 = b_lin [wave * 32 + ln15];
  const float bl1 = b_lin [wave * 32 + 16 + ln15];
  #pragma unroll
  for (int r = 0; r < 4; ++r)
    #pragma unroll
    for (int e = 0; e < 4; ++e) {
      accz[r][0][e] += bg0;
      accz[r][1][e] += bg1;
    }

  // ---- softmax over 256 cols per row (split across the 8 waves) ----
  #pragma unroll
  for (int r = 0; r < 4; ++r)
    #pragma unroll
    for (int e = 0; e < 4; ++e) {
      float v = fmaxf(accz[r][0][e], accz[r][1][e]);
      v = fmaxf(v, __shfl_xor(v, 1));
      v = fmaxf(v, __shfl_xor(v, 2));
      v = fmaxf(v, __shfl_xor(v, 4));
      v = fmaxf(v, __shfl_xor(v, 8));
      if (ln15 == 0) pmax[(r * 16 + quad * 4 + e) * 8 + wave] = v;
    }
  __syncthreads();
  #pragma unroll
  for (int r = 0; r < 4; ++r)
    #pragma unroll
    for (int e = 0; e < 4; ++e) {
      const int rl = r * 16 + quad * 4 + e;
      f32x4 m0 = *(const f32x4*)&pmax[rl * 8];
      f32x4 m1 = *(const f32x4*)&pmax[rl * 8 + 4];
      float fm = fmaxf(fmaxf(fmaxf(m0[0], m0[1]), fmaxf(m0[2], m0[3])),
                       fmaxf(fmaxf(m1[0], m1[1]), fmaxf(m1[2], m1[3])));
      float e0 = __expf(accz[r][0][e] - fm);
      float e1 = __expf(accz[r][1][e] - fm);
      accz[r][0][e] = e0;
      accz[r][1][e] = e1;
      float s = e0 + e1;
      s += __shfl_xor(s, 1);
      s += __shfl_xor(s, 2);
      s += __shfl_xor(s, 4);
      s += __shfl_xor(s, 8);
      if (ln15 == 0) psum[rl * 8 + wave] = s;
    }
  __syncthreads();
  #pragma unroll
  for (int r = 0; r < 4; ++r)
    #pragma unroll
    for (int e = 0; e < 4; ++e) {
      const int rl = r * 16 + quad * 4 + e;
      f32x4 s0 = *(const f32x4*)&psum[rl * 8];
      f32x4 s1 = *(const f32x4*)&psum[rl * 8 + 4];
      float inv = 1.0f / (s0[0] + s0[1] + s0[2] + s0[3] +
                          s1[0] + s1[1] + s1[2] + s1[3]);
      accs[r][0][e] = (accs[r][0][e] + bl0) * (accz[r][0][e] * inv);  // gated
      accs[r][1][e] = (accs[r][1][e] + bl1) * (accz[r][1][e] * inv);
    }

  // ---- segment pooling: masked reduce, quad shuffles, direct atomics ----
  const int b0 = batch_l[0], b1 = batch_l[63];
  for (int g = b0; g <= b1; ++g) {
    float cs0 = 0.0f, cs1 = 0.0f;
    #pragma unroll
    for (int r = 0; r < 4; ++r)
      #pragma unroll
      for (int e = 0; e < 4; ++e) {
        const int rl = r * 16 + quad * 4 + e;
        const float msk = (batch_l[rl] == g) ? 1.0f : 0.0f;
        cs0 = fmaf(accs[r][0][e], msk, cs0);
        cs1 = fmaf(accs[r][1][e], msk, cs1);
      }
    cs0 += __shfl_xor(cs0, 16); cs0 += __shfl_xor(cs0, 32);
    cs1 += __shfl_xor(cs1, 16); cs1 += __shfl_xor(cs1, 32);
    if (quad == 0) {
      atomicAdd(&sums[(size_t)g * 256 + wave * 32 + ln15], cs0);
      atomicAdd(&sums[(size_t)g * 256 + wave * 32 + 16 + ln15], cs1);
    }
  }
}

// ---------------------------------------------------------------------------
// finalize (in-place: io holds per-graph sums on entry, final output on exit)
// ---------------------------------------------------------------------------
__device__ __forceinline__ int lbound(const int* a, int n, int v) {
  int lo = 0, hi = n;
  while (lo < hi) {
    int mid = (lo + hi) >> 1;
    if (a[mid] < v) lo = mid + 1; else hi = mid;
  }
  return lo;
}

__global__ __launch_bounds__(256) void finalize(float* io,
                                                const int* __restrict__ batch, int N,
                                                const float* __restrict__ W_fin,
                                                const float* __restrict__ b_fin) {
  __shared__ __align__(16) float mrow[256];
  __shared__ float s_inv;
  const int g = blockIdx.x, tid = threadIdx.x;
  if (tid == 0) {
    int cnt = lbound(batch, N, g + 1) - lbound(batch, N, g);
    s_inv = 1.0f / fmaxf((float)cnt, 1.0f);
  }
  __syncthreads();
  mrow[tid] = io[(size_t)g * 256 + tid] * s_inv;
  __syncthreads();
  float acc = b_fin[tid];
  #pragma unroll 8
  for (int k = 0; k < 256; ++k)
    acc = fmaf(mrow[k], W_fin[k * 256 + tid], acc);
  io[(size_t)g * 256 + tid] = acc;
}

// ---------------------------------------------------------------------------
extern "C" void kernel_launch(void* const* d_in, const int* in_sizes, int n_in,
                              void* d_out, int out_size, void* d_ws, size_t ws_size,
                              hipStream_t stream) {
  const float* x      = (const float*)d_in[0];
  // d_in[1] = edge_index: unused by the reference
  const int*   batch  = (const int*)d_in[2];     // harness passes integers as int32
  const float* W_lin  = (const float*)d_in[3];
  const float* b_lin  = (const float*)d_in[4];
  const float* W_gate = (const float*)d_in[5];
  const float* b_gate = (const float*)d_in[6];
  const float* W_fin  = (const float*)d_in[7];
  const float* b_fin  = (const float*)d_in[8];
  float* out = (float*)d_out;                    // doubles as the sums buffer
  const int N = in_sizes[2];                     // 400000

  short* blob = (short*)d_ws;                    // 256 KB bf16 weight blob

  prep_w<<<16, 256, 0, stream>>>(W_gate, W_lin, blob, out);
  fused_main<<<N / 64, 512, 0, stream>>>(x, batch, b_lin, b_gate,
                                         (const short*)blob, out);
  finalize<<<512, 256, 0, stream>>>(out, batch, N, W_fin, b_fin);
}

// Round 3
// 720.876 us; speedup vs baseline: 1.0015x; 1.0015x over previous
//
#include <hip/hip_runtime.h>

// ---------------------------------------------------------------------------
// GraphAggregator v4: vmcnt-FIFO-correct pipeline + conflict-free LDS layout.
//  - x staged fp32 via global_load_lds, 4-slab rotation, DMA distance 3
//    (2 full phases of latency coverage).
//  - Per phase issue order: [B(ks+1) global->reg] then [DMA(ks+3)].
//    FIFO: the compiler's B(ks)-wait (vmcnt(6)) drains exactly D(ks+1)
//    (2 phases old, needed next phase) and leaves D(ks+2)/D(ks+3) in
//    flight. End-of-phase barrier = vmcnt(6)+lgkmcnt(0): a no-op in
//    steady state, only phase 0 actually waits. Never vmcnt(0) mid-loop.
//  - Slab layout [r][half][lane]: every A-fragment read is a contiguous
//    16B/lane ds_read_b128 (conflict-free); DMA source pre-swizzled,
//    LDS dest linear (m173 pattern).
//  - bf16 conversion at fragment-read time via v_cvt_pk_bf16_f32 (HW RNE).
// ---------------------------------------------------------------------------

typedef __attribute__((ext_vector_type(8))) short bf16x8;
typedef __attribute__((ext_vector_type(4))) float f32x4;

__device__ __forceinline__ short f2bf(float f) {
  unsigned u = __float_as_uint(f);
  unsigned r = (u + 0x7FFFu + ((u >> 16) & 1u)) >> 16;   // RNE
  return (short)r;
}

__device__ __forceinline__ void glds16f(float* ldst, const float* gsrc) {
  __builtin_amdgcn_global_load_lds(
      (const __attribute__((address_space(1))) void*)gsrc,
      (__attribute__((address_space(3))) void*)ldst,
      16, 0, 0);
}

// 8 fp32 -> bf16x8 via 4x v_cvt_pk_bf16_f32 (RNE in HW)
__device__ __forceinline__ bf16x8 cvt8(f32x4 lo, f32x4 hi) {
  union { unsigned u[4]; bf16x8 v; } cv;
  asm("v_cvt_pk_bf16_f32 %0, %4, %5\n\t"
      "v_cvt_pk_bf16_f32 %1, %6, %7\n\t"
      "v_cvt_pk_bf16_f32 %2, %8, %9\n\t"
      "v_cvt_pk_bf16_f32 %3, %10, %11"
      : "=&v"(cv.u[0]), "=&v"(cv.u[1]), "=&v"(cv.u[2]), "=&v"(cv.u[3])
      : "v"(lo[0]), "v"(lo[1]), "v"(lo[2]), "v"(lo[3]),
        "v"(hi[0]), "v"(hi[1]), "v"(hi[2]), "v"(hi[3]));
  return cv.v;
}

// ---------------------------------------------------------------------------
// prep_w: fp32 W[k][n] (256x256) -> bf16 blob in MFMA B-fragment order:
//   blob[mat][ks][ct*64+lane][j] = W[ks*32 + (lane>>4)*8 + j][ct*16 + (lane&15)]
// mat 0 = W_gate, mat 1 = W_lin. One block per (mat, ks) slice.
// Also zeroes the sums buffer (replaces hipMemsetAsync).
// ---------------------------------------------------------------------------
__global__ __launch_bounds__(256) void prep_w(const float* __restrict__ Wg,
                                              const float* __restrict__ Wl,
                                              short* __restrict__ blob,
                                              float* __restrict__ sums) {
  __shared__ __align__(16) float tile[32][260];
  const int b = blockIdx.x;
  const int mat = b >> 3, ks = b & 7;
  const float* W = mat ? Wl : Wg;
  const int tid = threadIdx.x;
  {
    f32x4 z = (f32x4)(0.0f);
    #pragma unroll
    for (int i = 0; i < 8; ++i)
      *(f32x4*)&sums[(size_t)(i * 4096 + b * 256 + tid) * 4] = z;
  }
  #pragma unroll
  for (int i = 0; i < 8; ++i) {
    int f4 = tid + i * 256;
    int kl = f4 >> 6;
    int c0 = (f4 & 63) * 4;
    f32x4 v = *(const f32x4*)&W[(ks * 32 + kl) * 256 + c0];
    tile[kl][c0 + 0] = v[0]; tile[kl][c0 + 1] = v[1];
    tile[kl][c0 + 2] = v[2]; tile[kl][c0 + 3] = v[3];
  }
  __syncthreads();
  #pragma unroll
  for (int i = 0; i < 4; ++i) {
    int chunk = tid + i * 256;           // ct*64 + lane
    int ln = chunk & 63;
    int n  = ((chunk >> 6) << 4) + (ln & 15);
    int k0 = (ln >> 4) * 8;
    bf16x8 o;
    #pragma unroll
    for (int j = 0; j < 8; ++j) o[j] = f2bf(tile[k0 + j][n]);
    *(bf16x8*)&blob[(size_t)(mat * 8 + ks) * 8192 + (size_t)chunk * 8] = o;
  }
}

// ---------------------------------------------------------------------------
// fused_main: 64 rows/block, 512 threads (8 waves), wave = col-group
// (32 cols x 2 mats). Per wave per phase: 4 A-frags x 4 B-frags, 16 MFMA.
// Slab (fp32, 2048 floats): float idx = (r*2 + h)*256 + lane*4 + j holds
//   x[row0 + r*16 + (lane&15)][ks*32 + (lane>>4)*8 + h*4 + j].
// Fragment read: lo = slab + r*512 + lane*4, hi = lo + 256 (both b128,
// 16B/lane contiguous -> conflict-free).
// DMA granule tid: r=tid>>7, h=(tid>>6)&1, l=tid&63; dest = wave-uniform
// slab + wave*256 (+ lane*16B by HW) = linear; source carries the swizzle.
// ---------------------------------------------------------------------------
__global__ __launch_bounds__(512, 4) void
fused_main(const float* __restrict__ x,
           const int* __restrict__ batch,
           const float* __restrict__ b_lin,
           const float* __restrict__ b_gate,
           const short* __restrict__ blob,
           float* __restrict__ sums) {
  __shared__ __align__(16) float xsf[4 * 2048];   // 4 fp32 slabs, 32 KB
  __shared__ __align__(16) float pmax[64 * 8];    // [row][wave] 2 KB
  __shared__ __align__(16) float psum[64 * 8];    // 2 KB
  __shared__ int batch_l[64];

  const int tid  = threadIdx.x;
  const int lane = tid & 63;
  const int wave = tid >> 6;            // col-group 0..7 (32 cols each)
  const int quad = lane >> 4;
  const int ln15 = lane & 15;
  const long long row0 = (long long)blockIdx.x * 64;

  // DMA source mapping (granule = tid)
  const int g_r = tid >> 7;
  const int g_h = (tid >> 6) & 1;
  const int g_l = tid & 63;
  const float* xsrc = x + (row0 + g_r * 16 + (g_l & 15)) * 256
                        + (g_l >> 4) * 8 + g_h * 4;
  float* dma_dst = xsf + wave * 256;    // wave-uniform; HW adds lane*16B

  const short* bptr = blob + (size_t)(wave * 128 + lane) * 8;

  // ---- prologue: batch tile, B(0) regs, DMAs for slabs 0,1,2 ----
  if (tid < 64) batch_l[tid] = batch[row0 + tid];
  bf16x8 bz0 = *(const bf16x8*)(bptr);
  bf16x8 bz1 = *(const bf16x8*)(bptr + 512);
  bf16x8 bs0 = *(const bf16x8*)(bptr + (size_t)8 * 8192);
  bf16x8 bs1 = *(const bf16x8*)(bptr + (size_t)8 * 8192 + 512);
  __builtin_amdgcn_sched_barrier(0);
  glds16f(dma_dst,            xsrc);            // D0
  glds16f(dma_dst + 2048,     xsrc + 32);       // D1
  glds16f(dma_dst + 2 * 2048, xsrc + 64);       // D2
  asm volatile("s_waitcnt vmcnt(2) lgkmcnt(0)\ns_barrier" ::: "memory");

  f32x4 accz[4][2], accs[4][2];
  #pragma unroll
  for (int r = 0; r < 4; ++r)
    #pragma unroll
    for (int c = 0; c < 2; ++c) {
      accz[r][c] = (f32x4)(0.0f);
      accs[r][c] = (f32x4)(0.0f);
    }

  #pragma unroll
  for (int ks = 0; ks < 8; ++ks) {
    // 1) B(ks+1) prefetch FIRST (older in vmcnt FIFO than the DMA below)
    bf16x8 nz0, nz1, ns0, ns1;
    if (ks < 7) {
      nz0 = *(const bf16x8*)(bptr + (size_t)(ks + 1) * 8192);
      nz1 = *(const bf16x8*)(bptr + (size_t)(ks + 1) * 8192 + 512);
      ns0 = *(const bf16x8*)(bptr + (size_t)(9 + ks) * 8192);
      ns1 = *(const bf16x8*)(bptr + (size_t)(9 + ks) * 8192 + 512);
    }
    __builtin_amdgcn_sched_barrier(0);
    // 2) x-DMA distance 3
    if (ks < 5)
      glds16f(xsf + ((ks + 3) & 3) * 2048 + wave * 256, xsrc + (ks + 3) * 32);
    __builtin_amdgcn_sched_barrier(0);
    // 3) compute phase ks (B(ks)-wait drains exactly D(ks+1))
    const float* xb = xsf + (ks & 3) * 2048;
    #pragma unroll
    for (int r = 0; r < 4; ++r) {
      f32x4 lo = *(const f32x4*)(xb + r * 512 + lane * 4);
      f32x4 hi = *(const f32x4*)(xb + r * 512 + 256 + lane * 4);
      bf16x8 a = cvt8(lo, hi);
      accz[r][0] = __builtin_amdgcn_mfma_f32_16x16x32_bf16(a, bz0, accz[r][0], 0, 0, 0);
      accz[r][1] = __builtin_amdgcn_mfma_f32_16x16x32_bf16(a, bz1, accz[r][1], 0, 0, 0);
      accs[r][0] = __builtin_amdgcn_mfma_f32_16x16x32_bf16(a, bs0, accs[r][0], 0, 0, 0);
      accs[r][1] = __builtin_amdgcn_mfma_f32_16x16x32_bf16(a, bs1, accs[r][1], 0, 0, 0);
    }
    if (ks < 7) {
      bz0 = nz0; bz1 = nz1; bs0 = ns0; bs1 = ns1;
      // allow B(ks+1)x4 + D(ks+2) + D(ks+3) to stay outstanding
      asm volatile("s_waitcnt vmcnt(6) lgkmcnt(0)\ns_barrier" ::: "memory");
    }
  }

  // ---- biases ----
  const float bg0 = b_gate[wave * 32 + ln15];
  const float bg1 = b_gate[wave * 32 + 16 + ln15];
  const float bl0 = b_lin [wave * 32 + ln15];
  const float bl1 = b_lin [wave * 32 + 16 + ln15];
  #pragma unroll
  for (int r = 0; r < 4; ++r)
    #pragma unroll
    for (int e = 0; e < 4; ++e) {
      accz[r][0][e] += bg0;
      accz[r][1][e] += bg1;
    }

  // ---- softmax over 256 cols per row (split across the 8 waves) ----
  #pragma unroll
  for (int r = 0; r < 4; ++r)
    #pragma unroll
    for (int e = 0; e < 4; ++e) {
      float v = fmaxf(accz[r][0][e], accz[r][1][e]);
      v = fmaxf(v, __shfl_xor(v, 1));
      v = fmaxf(v, __shfl_xor(v, 2));
      v = fmaxf(v, __shfl_xor(v, 4));
      v = fmaxf(v, __shfl_xor(v, 8));
      if (ln15 == 0) pmax[(r * 16 + quad * 4 + e) * 8 + wave] = v;
    }
  __syncthreads();
  #pragma unroll
  for (int r = 0; r < 4; ++r)
    #pragma unroll
    for (int e = 0; e < 4; ++e) {
      const int rl = r * 16 + quad * 4 + e;
      f32x4 m0 = *(const f32x4*)&pmax[rl * 8];
      f32x4 m1 = *(const f32x4*)&pmax[rl * 8 + 4];
      float fm = fmaxf(fmaxf(fmaxf(m0[0], m0[1]), fmaxf(m0[2], m0[3])),
                       fmaxf(fmaxf(m1[0], m1[1]), fmaxf(m1[2], m1[3])));
      float e0 = __expf(accz[r][0][e] - fm);
      float e1 = __expf(accz[r][1][e] - fm);
      accz[r][0][e] = e0;
      accz[r][1][e] = e1;
      float s = e0 + e1;
      s += __shfl_xor(s, 1);
      s += __shfl_xor(s, 2);
      s += __shfl_xor(s, 4);
      s += __shfl_xor(s, 8);
      if (ln15 == 0) psum[rl * 8 + wave] = s;
    }
  __syncthreads();
  #pragma unroll
  for (int r = 0; r < 4; ++r)
    #pragma unroll
    for (int e = 0; e < 4; ++e) {
      const int rl = r * 16 + quad * 4 + e;
      f32x4 s0 = *(const f32x4*)&psum[rl * 8];
      f32x4 s1 = *(const f32x4*)&psum[rl * 8 + 4];
      float inv = 1.0f / (s0[0] + s0[1] + s0[2] + s0[3] +
                          s1[0] + s1[1] + s1[2] + s1[3]);
      accs[r][0][e] = (accs[r][0][e] + bl0) * (accz[r][0][e] * inv);  // gated
      accs[r][1][e] = (accs[r][1][e] + bl1) * (accz[r][1][e] * inv);
    }

  // ---- segment pooling: masked reduce, quad shuffles, direct atomics ----
  const int b0 = batch_l[0], b1 = batch_l[63];
  for (int g = b0; g <= b1; ++g) {
    float cs0 = 0.0f, cs1 = 0.0f;
    #pragma unroll
    for (int r = 0; r < 4; ++r)
      #pragma unroll
      for (int e = 0; e < 4; ++e) {
        const int rl = r * 16 + quad * 4 + e;
        const float msk = (batch_l[rl] == g) ? 1.0f : 0.0f;
        cs0 = fmaf(accs[r][0][e], msk, cs0);
        cs1 = fmaf(accs[r][1][e], msk, cs1);
      }
    cs0 += __shfl_xor(cs0, 16); cs0 += __shfl_xor(cs0, 32);
    cs1 += __shfl_xor(cs1, 16); cs1 += __shfl_xor(cs1, 32);
    if (quad == 0) {
      atomicAdd(&sums[(size_t)g * 256 + wave * 32 + ln15], cs0);
      atomicAdd(&sums[(size_t)g * 256 + wave * 32 + 16 + ln15], cs1);
    }
  }
}

// ---------------------------------------------------------------------------
// finalize (in-place: io holds per-graph sums on entry, final output on exit)
// ---------------------------------------------------------------------------
__device__ __forceinline__ int lbound(const int* a, int n, int v) {
  int lo = 0, hi = n;
  while (lo < hi) {
    int mid = (lo + hi) >> 1;
    if (a[mid] < v) lo = mid + 1; else hi = mid;
  }
  return lo;
}

__global__ __launch_bounds__(256) void finalize(float* io,
                                                const int* __restrict__ batch, int N,
                                                const float* __restrict__ W_fin,
                                                const float* __restrict__ b_fin) {
  __shared__ __align__(16) float mrow[256];
  __shared__ float s_inv;
  const int g = blockIdx.x, tid = threadIdx.x;
  if (tid == 0) {
    int cnt = lbound(batch, N, g + 1) - lbound(batch, N, g);
    s_inv = 1.0f / fmaxf((float)cnt, 1.0f);
  }
  __syncthreads();
  mrow[tid] = io[(size_t)g * 256 + tid] * s_inv;
  __syncthreads();
  float acc = b_fin[tid];
  #pragma unroll 8
  for (int k = 0; k < 256; ++k)
    acc = fmaf(mrow[k], W_fin[k * 256 + tid], acc);
  io[(size_t)g * 256 + tid] = acc;
}

// ---------------------------------------------------------------------------
extern "C" void kernel_launch(void* const* d_in, const int* in_sizes, int n_in,
                              void* d_out, int out_size, void* d_ws, size_t ws_size,
                              hipStream_t stream) {
  const float* x      = (const float*)d_in[0];
  // d_in[1] = edge_index: unused by the reference
  const int*   batch  = (const int*)d_in[2];     // harness passes integers as int32
  const float* W_lin  = (const float*)d_in[3];
  const float* b_lin  = (const float*)d_in[4];
  const float* W_gate = (const float*)d_in[5];
  const float* b_gate = (const float*)d_in[6];
  const float* W_fin  = (const float*)d_in[7];
  const float* b_fin  = (const float*)d_in[8];
  float* out = (float*)d_out;                    // doubles as the sums buffer
  const int N = in_sizes[2];                     // 400000

  short* blob = (short*)d_ws;                    // 256 KB bf16 weight blob

  prep_w<<<16, 256, 0, stream>>>(W_gate, W_lin, blob, out);
  fused_main<<<N / 64, 512, 0, stream>>>(x, batch, b_lin, b_gate,
                                         (const short*)blob, out);
  finalize<<<512, 256, 0, stream>>>(out, batch, N, W_fin, b_fin);
}